// Round 7
// baseline (347.336 us; speedup 1.0000x reference)
//
#include <hip/hip_runtime.h>

#define BB 64
#define TT 512
#define HH 1024
#define CC 21
#define NROWS (BB*TT)   // 32768
#define TSTR 68         // LDS tile row stride (floats): 272B = 16B-aligned, even banks

typedef __attribute__((ext_vector_type(8)))  short  short8;   // 8 bf16
typedef __attribute__((ext_vector_type(16))) float  float16;  // 32x32 MFMA acc

// ---------------------------------------------------------------------------
// Kernel 0: pre-format W into exact MFMA B-fragment order, split bf16 hi/lo.
// wf[q*512 + lane*8 + j] = bf16hi(W[k][n]), k = q*16 + (lane>>5)*8 + j,
// n = lane&31 (0 for n>=21); lo at +32768. B-frag loads in the GEMM become
// lane-contiguous 16B (perfectly coalesced), vs R6's 32-line scatter.
// ---------------------------------------------------------------------------
__global__ __launch_bounds__(256) void wprep(const float* __restrict__ W,
                                             unsigned short* __restrict__ wf) {
  int idx = blockIdx.x * 256 + threadIdx.x;   // 32768 = 64q * 64lane * 8j
  int q = idx >> 9;
  int l = (idx >> 3) & 63;
  int j = idx & 7;
  int k = q * 16 + (l >> 5) * 8 + j;
  int n = l & 31;
  float v = (n < CC) ? W[k * CC + n] : 0.f;
  unsigned b = __float_as_uint(v);
  float lo = v - __uint_as_float(b & 0xFFFF0000u);
  wf[idx]         = (unsigned short)(b >> 16);
  wf[32768 + idx] = (unsigned short)(__float_as_uint(lo) >> 16);
}

// ---------------------------------------------------------------------------
// Kernel 1: emissions = hs @ W + b via split-bf16 MFMA, ALL-COALESCED.
// 1024 blocks x 64 threads (1 wave, 32-row tile, K=1024).
// R6's lesson: per-lane-row streaming = 32-64 cache lines PER LOAD -> ~68us.
// Here: A chunk (32rows x 64k) staged coalesced float4->LDS (dbuf, stride 68,
// no barrier needed: single wave, DS in-order), A-frags via ds_read_b128;
// W-frags lane-contiguous from wprep's layout (L2/L3-broadcast across blocks).
// 3 MFMA per 16-k step (hi*hi + hi*lo + lo*hi).
// Frag conventions identical to R6 (passed absmax 0.0156).
// ---------------------------------------------------------------------------
__global__ __launch_bounds__(64) void emis_mfma(const float* __restrict__ hs,
                                                const unsigned short* __restrict__ wfrag,
                                                const float* __restrict__ bias,
                                                float* __restrict__ out) {
  __shared__ float tile[2][32 * TSTR];        // 17.4 KB
  const int lane = threadIdx.x;
  const int m = lane & 31, h = lane >> 5;
  const int row0 = blockIdx.x * 32;
  const int r_ = lane >> 4;                   // row-in-group-of-4
  const int sg = lane & 15;                   // 16B segment within 256B row-chunk

  if (blockIdx.x == 0 && lane == 0) out[(size_t)NROWS * CC] = 0.f;  // loss slot

  float16 acc;
#pragma unroll
  for (int i = 0; i < 16; ++i) acc[i] = 0.f;

  float4 buf[8];
#pragma unroll
  for (int i = 0; i < 8; ++i)                 // chunk 0: coalesced (4 rows/instr)
    buf[i] = *reinterpret_cast<const float4*>(
        hs + (size_t)(row0 + 4 * i + r_) * HH + sg * 4);
#pragma unroll
  for (int i = 0; i < 8; ++i)
    *reinterpret_cast<float4*>(&tile[0][(4 * i + r_) * TSTR + sg * 4]) = buf[i];

  for (int c = 0; c < 16; ++c) {
    const int pb = c & 1;
    if (c < 15) {                             // prefetch chunk c+1 into regs
#pragma unroll
      for (int i = 0; i < 8; ++i)
        buf[i] = *reinterpret_cast<const float4*>(
            hs + (size_t)(row0 + 4 * i + r_) * HH + (c + 1) * 64 + sg * 4);
    }
#pragma unroll
    for (int s = 0; s < 4; ++s) {
      const float* ap = &tile[pb][m * TSTR + s * 16 + h * 8];
      float4 a0 = *reinterpret_cast<const float4*>(ap);
      float4 a1 = *reinterpret_cast<const float4*>(ap + 4);
      float af[8] = {a0.x, a0.y, a0.z, a0.w, a1.x, a1.y, a1.z, a1.w};
      short8 ah, al;
#pragma unroll
      for (int jj = 0; jj < 8; ++jj) {
        unsigned b = __float_as_uint(af[jj]);
        ah[jj] = (short)(b >> 16);
        float lo = af[jj] - __uint_as_float(b & 0xFFFF0000u);
        al[jj] = (short)(__float_as_uint(lo) >> 16);
      }
      const int q = c * 4 + s;
      short8 bh = *reinterpret_cast<const short8*>(wfrag + q * 512 + lane * 8);
      short8 bl = *reinterpret_cast<const short8*>(wfrag + 32768 + q * 512 + lane * 8);
      acc = __builtin_amdgcn_mfma_f32_32x32x16_bf16(ah, bh, acc, 0, 0, 0);
      acc = __builtin_amdgcn_mfma_f32_32x32x16_bf16(ah, bl, acc, 0, 0, 0);
      acc = __builtin_amdgcn_mfma_f32_32x32x16_bf16(al, bh, acc, 0, 0, 0);
    }
    if (c < 15) {
#pragma unroll
      for (int i = 0; i < 8; ++i)
        *reinterpret_cast<float4*>(&tile[pb ^ 1][(4 * i + r_) * TSTR + sg * 4]) = buf[i];
    }
  }

  float bv = (m < CC) ? bias[m] : 0.f;
#pragma unroll
  for (int r = 0; r < 16; ++r) {
    int row = (r & 3) + 8 * (r >> 2) + 4 * h;   // m101-verified C/D mapping
    if (m < CC) out[(size_t)(row0 + row) * CC + m] = acc[r] + bv;
  }
}

// ---------------------------------------------------------------------------
// Kernel 2: CRF NLL — two-ended prob-space scan, FULLY SCALARIZED.
// R1's crf VGPR_Count=28 proves E[21]/F[21]/state arrays lived in SCRATCH
// (global memory!) — ~42 scratch loads per step was the real cost. All
// 21-element arrays are macro-expanded into named registers; no lambdas.
// ---------------------------------------------------------------------------
#define REP21(X) X(0) X(1) X(2) X(3) X(4) X(5) X(6) X(7) X(8) X(9) X(10) \
                 X(11) X(12) X(13) X(14) X(15) X(16) X(17) X(18) X(19) X(20)

#define DE(i)  float E##i = __builtin_amdgcn_exp2f(trans[(i) * CC + j] * L2E);
#define DF(i)  float F##i = __builtin_amdgcn_exp2f(trans[j * CC + (i)] * L2E);
#define DSF(i) float sf##i = __int_as_float(__builtin_amdgcn_readlane(__float_as_int(f), i));
#define ASF(i) sf##i = __int_as_float(__builtin_amdgcn_readlane(__float_as_int(f), i));
#define DSH(i) float sh##i = __int_as_float(__builtin_amdgcn_readlane(__float_as_int(h_), i));

__global__ __launch_bounds__(128) void crf_kernel(const float* __restrict__ em,
                                                  const float* __restrict__ trans,
                                                  const float* __restrict__ startT,
                                                  const float* __restrict__ endT,
                                                  const int* __restrict__ att,
                                                  const int* __restrict__ labels,
                                                  float* __restrict__ loss) {
  const int b    = blockIdx.x;
  const int tid  = threadIdx.x;
  const int wave = tid >> 6;
  const int lane = tid & 63;
  __shared__ float sh_num;
  __shared__ int   sh_len;

  const float L2E = 1.4426950408889634f;
  const float LN2 = 0.6931471805599453f;

  if (wave == 1) {
    int cnt = 0;
    for (int t = lane; t < TT; t += 64) {
      bool mm = (t == 0) || ((att[b * TT + t] != 0) && (labels[b * TT + t] != -100));
      cnt += mm ? 1 : 0;
    }
#pragma unroll
    for (int off = 32; off >= 1; off >>= 1) cnt += __shfl_down(cnt, off);
    cnt = __shfl(cnt, 0);

    float s = 0.f;
    for (int t = lane + 1; t < TT; t += 64) {
      bool mm = (att[b * TT + t] != 0) && (labels[b * TT + t] != -100);
      if (mm) {
        int tp = labels[b * TT + t - 1], tc = labels[b * TT + t];
        s += trans[tp * CC + tc] + em[((size_t)b * TT + t) * CC + tc];
      }
    }
#pragma unroll
    for (int off = 32; off >= 1; off >>= 1) s += __shfl_down(s, off);
    if (lane == 0) {
      int tag0 = labels[b * TT];
      int lastTag = labels[b * TT + cnt - 1];
      s += startT[tag0] + em[((size_t)b * TT) * CC + tag0] + endT[lastTag];
      sh_num = s;
      sh_len = cnt;
    }
  }

  const int j = lane < CC ? lane : CC - 1;
  REP21(DE)                                   // E col j (fwd)
  REP21(DF)                                   // E row j (bwd)
  float f = __builtin_amdgcn_exp2f((startT[j] + em[((size_t)b * TT) * CC + j]) * L2E);
  float g = __builtin_amdgcn_exp2f(endT[j] * L2E);
  __syncthreads();
  if (wave != 0) return;

  const int len = sh_len;
  const int L  = len - 1;
  const int mF = (L + 1) >> 1;
  const int mB = L - mF;
  int kf = 0, kg = 0;

  REP21(DSF)

  const float* emB = em + (size_t)b * TT * CC;

  float rf[4], rb[4];
#pragma unroll
  for (int u = 0; u < 4; ++u) {
    int tf = 1 + u; if (tf > TT - 1) tf = TT - 1;
    rf[u] = emB[(size_t)tf * CC + j];
    int tb = len - 1 - u; if (tb < 0) tb = 0;
    rb[u] = emB[(size_t)tb * CC + j];
  }

  int it = 0;
  while (it < mF) {
#pragma unroll
    for (int u = 0; u < 4; ++u) {
      const int i2 = it + u;
      if (i2 < mF) {                 // ---- forward: f' = (E^T f) .* pm ----
        float pm = __builtin_amdgcn_exp2f(rf[u] * L2E);
        int tp = 1 + i2 + 4; if (tp > TT - 1) tp = TT - 1;
        rf[u] = emB[(size_t)tp * CC + j];
        int ef = (__float_as_int(sf0) >> 23) & 255;
        kf += ef - 127;
        float pms = pm * __int_as_float((254 - ef) << 23);
        float c0 = sf0 * E0, c1 = sf1 * E1, c2 = sf2 * E2;
        c0 = fmaf(sf3,  E3,  c0); c1 = fmaf(sf4,  E4,  c1); c2 = fmaf(sf5,  E5,  c2);
        c0 = fmaf(sf6,  E6,  c0); c1 = fmaf(sf7,  E7,  c1); c2 = fmaf(sf8,  E8,  c2);
        c0 = fmaf(sf9,  E9,  c0); c1 = fmaf(sf10, E10, c1); c2 = fmaf(sf11, E11, c2);
        c0 = fmaf(sf12, E12, c0); c1 = fmaf(sf13, E13, c1); c2 = fmaf(sf14, E14, c2);
        c0 = fmaf(sf15, E15, c0); c1 = fmaf(sf16, E16, c1); c2 = fmaf(sf17, E17, c2);
        c0 = fmaf(sf18, E18, c0); c1 = fmaf(sf19, E19, c1); c2 = fmaf(sf20, E20, c2);
        f = ((c0 + c1) + c2) * pms;
        REP21(ASF)
      }
      if (i2 < mB) {                 // ---- backward: g' = E (pm .* g) ----
        float pm = __builtin_amdgcn_exp2f(rb[u] * L2E);
        int tb = len - 1 - i2 - 4; if (tb < 0) tb = 0;
        rb[u] = emB[(size_t)tb * CC + j];
        float h_ = pm * g;
        REP21(DSH)
        int eg = (__float_as_int(sh0) >> 23) & 255;
        kg += eg - 127;
        float sB = __int_as_float((254 - eg) << 23);
        float d0 = sh0 * F0, d1 = sh1 * F1, d2 = sh2 * F2;
        d0 = fmaf(sh3,  F3,  d0); d1 = fmaf(sh4,  F4,  d1); d2 = fmaf(sh5,  F5,  d2);
        d0 = fmaf(sh6,  F6,  d0); d1 = fmaf(sh7,  F7,  d1); d2 = fmaf(sh8,  F8,  d2);
        d0 = fmaf(sh9,  F9,  d0); d1 = fmaf(sh10, F10, d1); d2 = fmaf(sh11, F11, d2);
        d0 = fmaf(sh12, F12, d0); d1 = fmaf(sh13, F13, d1); d2 = fmaf(sh14, F14, d2);
        d0 = fmaf(sh15, F15, d0); d1 = fmaf(sh16, F16, d1); d2 = fmaf(sh17, F17, d2);
        d0 = fmaf(sh18, F18, d0); d1 = fmaf(sh19, F19, d1); d2 = fmaf(sh20, F20, d2);
        g = ((d0 + d1) + d2) * sB;
      }
    }
    it += 4;
  }

  float v = (lane < CC) ? f * g : 0.f;        // Z = f.g * 2^(kf+kg)
#pragma unroll
  for (int off = 32; off >= 1; off >>= 1) v += __shfl_xor(v, off);
  if (lane == 0) {
    float logZ = (float)(kf + kg) * LN2 + LN2 * __builtin_amdgcn_logf(v);
    atomicAdd(loss, -(sh_num - logZ) * (1.0f / 64.0f));
  }
}

extern "C" void kernel_launch(void* const* d_in, const int* in_sizes, int n_in,
                              void* d_out, int out_size, void* d_ws, size_t ws_size,
                              hipStream_t stream) {
  const float* hs     = (const float*)d_in[0];
  const float* W      = (const float*)d_in[1];
  const float* bias   = (const float*)d_in[2];
  const float* trans  = (const float*)d_in[3];
  const float* startT = (const float*)d_in[4];
  const float* endT   = (const float*)d_in[5];
  const int*   att    = (const int*)d_in[6];
  const int*   labels = (const int*)d_in[7];
  float* out = (float*)d_out;
  unsigned short* wfrag = (unsigned short*)d_ws;   // 128 KB

  wprep<<<dim3(128), dim3(256), 0, stream>>>(W, wfrag);
  emis_mfma<<<dim3(1024), dim3(64), 0, stream>>>(hs, wfrag, bias, out);
  crf_kernel<<<dim3(64), dim3(128), 0, stream>>>(out, trans, startT, endT, att,
                                                 labels, out + (size_t)NROWS * CC);
}